// Round 1
// baseline (593.765 us; speedup 1.0000x reference)
//
#include <hip/hip_runtime.h>

// SSM DPLR kernel: K[h,l] = 2*Re(C_h . dA_h^l . dB_h)
// dA collapses to diag(g) + q r^T (Mobius of diag+rank1 is diag+rank1).
// One head per 64-lane wave; state x_n lives in lane n's registers.

#define NN   64
#define LL   2048

struct C2 { float re, im; };

__device__ __forceinline__ C2 cmul(C2 a, C2 b) {
    return { a.re*b.re - a.im*b.im, a.re*b.im + a.im*b.re };
}
__device__ __forceinline__ C2 cadd(C2 a, C2 b) { return { a.re+b.re, a.im+b.im }; }
__device__ __forceinline__ C2 csub(C2 a, C2 b) { return { a.re-b.re, a.im-b.im }; }
__device__ __forceinline__ C2 cinv(C2 a) {
    float inv = 1.0f / (a.re*a.re + a.im*a.im);
    return { a.re*inv, -a.im*inv };
}
__device__ __forceinline__ C2 cscale(float s, C2 a) { return { s*a.re, s*a.im }; }

__global__ __launch_bounds__(64) void ssm_dplr_kernel(
    const float* __restrict__ A_real, const float* __restrict__ A_imag,
    const float* __restrict__ B_real, const float* __restrict__ B_imag,
    const float* __restrict__ P_real, const float* __restrict__ P_imag,
    const float* __restrict__ C_real, const float* __restrict__ C_imag,
    const float* __restrict__ log_dt, float* __restrict__ out)
{
    const int h = blockIdx.x;      // head, 0..255
    const int n = threadIdx.x;     // state element, 0..63
    const int idx = h * NN + n;    // P/C have leading dim RANK=CH=1 -> same idx

    const float dt = expf(log_dt[h]);
    const float c  = 0.5f * dt;

    // Lambda = -A_real - i*A_imag
    const C2 lam = { -A_real[idx], -A_imag[idx] };
    const C2 p   = { P_real[idx], P_imag[idx] };
    const C2 Bv  = { B_real[idx], B_imag[idx] };
    const C2 Cv  = { C_real[idx], C_imag[idx] };
    const C2 pc  = { p.re, -p.im };          // conj(p)

    // D = I - c*Lambda (diagonal), d = 1/den; E = I + c*Lambda
    const C2 den = { 1.0f - c*lam.re, -c*lam.im };
    const C2 d   = cinv(den);
    const C2 e   = { 1.0f + c*lam.re, c*lam.im };
    const C2 g   = cmul(d, e);               // diagonal of dA

    // Wave reductions: s = sum_n d_n |p_n|^2 ; u = sum_n d_n conj(p_n) B_n
    const float p2 = p.re*p.re + p.im*p.im;
    C2 sv = cscale(p2, d);
    C2 uv = cmul(cmul(d, pc), Bv);
    #pragma unroll
    for (int off = 32; off > 0; off >>= 1) {
        sv.re += __shfl_xor(sv.re, off);
        sv.im += __shfl_xor(sv.im, off);
        uv.re += __shfl_xor(uv.re, off);
        uv.im += __shfl_xor(uv.im, off);
    }

    // beta = c / (1 + c*s);  gamma = -c*(1 - beta*s)
    const C2 one_cs = { 1.0f + c*sv.re, c*sv.im };
    const C2 beta   = cscale(c, cinv(one_cs));
    const C2 bs     = cmul(beta, sv);
    const C2 gamma  = { -c*(1.0f - bs.re), c*bs.im };

    // dA = diag(g) + q r^T
    const C2 q = cmul(d, p);
    const C2 r = cmul(pc, csub(gamma, cmul(beta, g)));

    // x0 = dB = dt*( d .* B - beta*u * q )
    C2 x = cscale(dt, csub(cmul(d, Bv), cmul(cmul(beta, uv), q)));

    float* outh = out + h * LL;

    for (int l = 0; l < LL; ++l) {
        // sigma = r . x (plain dot, no conj); kdot = Re(C . x)
        float tr = r.re*x.re - r.im*x.im;
        float ti = r.re*x.im + r.im*x.re;
        float tk = Cv.re*x.re - Cv.im*x.im;
        #pragma unroll
        for (int off = 32; off > 0; off >>= 1) {
            tr += __shfl_xor(tr, off);
            ti += __shfl_xor(ti, off);
            tk += __shfl_xor(tk, off);
        }
        if (n == 0) outh[l] = 2.0f * tk;
        // x = g .* x + q * sigma
        const float nr = g.re*x.re - g.im*x.im + q.re*tr - q.im*ti;
        const float ni = g.re*x.im + g.im*x.re + q.re*ti + q.im*tr;
        x.re = nr; x.im = ni;
    }
}

extern "C" void kernel_launch(void* const* d_in, const int* in_sizes, int n_in,
                              void* d_out, int out_size, void* d_ws, size_t ws_size,
                              hipStream_t stream) {
    const float* A_real = (const float*)d_in[0];
    const float* A_imag = (const float*)d_in[1];
    const float* B_real = (const float*)d_in[2];
    const float* B_imag = (const float*)d_in[3];
    const float* P_real = (const float*)d_in[4];
    const float* P_imag = (const float*)d_in[5];
    const float* C_real = (const float*)d_in[6];
    const float* C_imag = (const float*)d_in[7];
    const float* log_dt = (const float*)d_in[8];
    float* out = (float*)d_out;

    ssm_dplr_kernel<<<256, 64, 0, stream>>>(
        A_real, A_imag, B_real, B_imag, P_real, P_imag,
        C_real, C_imag, log_dt, out);
}

// Round 2
// 306.133 us; speedup vs baseline: 1.9396x; 1.9396x over previous
//
#include <hip/hip_runtime.h>

// SSM DPLR kernel: K[h,l] = 2*Re(C_h . dA_h^l . dB_h)
// dA = diag(g) + q r^T (Mobius transform of diag+rank1 stays diag+rank1).
// One head per 64-lane wave; state x_n in lane n's registers.
// R1: wave reduction via DPP (VALU pipe, ~8 cyc/stage) instead of
//     __shfl_xor (ds_swizzle, ~100 cyc/stage).

#define NN   64
#define LL   2048

struct C2 { float re, im; };

__device__ __forceinline__ C2 cmul(C2 a, C2 b) {
    return { a.re*b.re - a.im*b.im, a.re*b.im + a.im*b.re };
}
__device__ __forceinline__ C2 csub(C2 a, C2 b) { return { a.re-b.re, a.im-b.im }; }
__device__ __forceinline__ C2 cinv(C2 a) {
    float inv = 1.0f / (a.re*a.re + a.im*a.im);
    return { a.re*inv, -a.im*inv };
}
__device__ __forceinline__ C2 cscale(float s, C2 a) { return { s*a.re, s*a.im }; }

// DPP-based add of cross-lane partner. ctrl encodings:
//  0xB1 quad_perm[1,0,3,2] (xor1), 0x4E quad_perm[2,3,0,1] (xor2),
//  0x124 row_ror:4, 0x128 row_ror:8, 0x142 row_bcast:15, 0x143 row_bcast:31
template<int CTRL>
__device__ __forceinline__ float dpp_add(float x) {
    int t = __builtin_amdgcn_update_dpp(0, __float_as_int(x), CTRL, 0xF, 0xF, true);
    return x + __int_as_float(t);
}

// After this sequence lane 63 holds the full 64-lane sum.
__device__ __forceinline__ float wave_sum_to_lane63(float x) {
    x = dpp_add<0xB1>(x);   // + xor1   (quad pairs)
    x = dpp_add<0x4E>(x);   // + xor2   (quad totals in all 4)
    x = dpp_add<0x124>(x);  // + ror4   (quad + neighbor quad)
    x = dpp_add<0x128>(x);  // + ror8   (full 16-lane row sum, all lanes)
    x = dpp_add<0x142>(x);  // row_bcast15: row1+=row0, row3+=row2
    x = dpp_add<0x143>(x);  // row_bcast31: rows2,3 += (row0+row1)
    return x;               // lane 63: total
}

__global__ __launch_bounds__(64) void ssm_dplr_kernel(
    const float* __restrict__ A_real, const float* __restrict__ A_imag,
    const float* __restrict__ B_real, const float* __restrict__ B_imag,
    const float* __restrict__ P_real, const float* __restrict__ P_imag,
    const float* __restrict__ C_real, const float* __restrict__ C_imag,
    const float* __restrict__ log_dt, float* __restrict__ out)
{
    const int h = blockIdx.x;      // head, 0..255
    const int n = threadIdx.x;     // state element, 0..63
    const int idx = h * NN + n;

    const float dt = expf(log_dt[h]);
    const float c  = 0.5f * dt;

    const C2 lam = { -A_real[idx], -A_imag[idx] };
    const C2 p   = { P_real[idx], P_imag[idx] };
    const C2 Bv  = { B_real[idx], B_imag[idx] };
    const C2 Cv  = { C_real[idx], C_imag[idx] };
    const C2 pc  = { p.re, -p.im };

    const C2 den = { 1.0f - c*lam.re, -c*lam.im };
    const C2 d   = cinv(den);
    const C2 e   = { 1.0f + c*lam.re, c*lam.im };
    const C2 g   = cmul(d, e);               // diagonal of dA

    // setup reductions (once; shuffle latency irrelevant here)
    const float p2 = p.re*p.re + p.im*p.im;
    C2 sv = cscale(p2, d);
    C2 uv = cmul(cmul(d, pc), Bv);
    #pragma unroll
    for (int off = 32; off > 0; off >>= 1) {
        sv.re += __shfl_xor(sv.re, off);
        sv.im += __shfl_xor(sv.im, off);
        uv.re += __shfl_xor(uv.re, off);
        uv.im += __shfl_xor(uv.im, off);
    }

    const C2 one_cs = { 1.0f + c*sv.re, c*sv.im };
    const C2 beta   = cscale(c, cinv(one_cs));
    const C2 bs     = cmul(beta, sv);
    const C2 gamma  = { -c*(1.0f - bs.re), c*bs.im };

    const C2 q = cmul(d, p);
    const C2 r = cmul(pc, csub(gamma, cmul(beta, g)));

    // x0 = dB = dt*( d .* B - beta*u * q )
    C2 x = cscale(dt, csub(cmul(d, Bv), cmul(cmul(beta, uv), q)));

    float* outh = out + h * LL;
    const bool is63 = (n == 63);

    for (int l = 0; l < LL; ++l) {
        // sigma = r . x (no conj); kdot = Re(C . x)
        float tr = r.re*x.re - r.im*x.im;
        float ti = r.re*x.im + r.im*x.re;
        float tk = Cv.re*x.re - Cv.im*x.im;
        tr = wave_sum_to_lane63(tr);
        ti = wave_sum_to_lane63(ti);
        tk = wave_sum_to_lane63(tk);
        if (is63) outh[l] = 2.0f * tk;
        const float TR = __builtin_amdgcn_readlane(__float_as_int(tr), 63) == 0 ? 0.0f : 0.0f, _unused = 0.0f; // placeholder avoided below
        (void)TR; (void)_unused;
        const float sr = __int_as_float(__builtin_amdgcn_readlane(__float_as_int(tr), 63));
        const float si = __int_as_float(__builtin_amdgcn_readlane(__float_as_int(ti), 63));
        // x = g .* x + q * sigma
        const float t1 = g.re*x.re - g.im*x.im;
        const float t2 = g.re*x.im + g.im*x.re;
        x.re = fmaf(-q.im, si, fmaf(q.re, sr, t1));
        x.im = fmaf( q.im, sr, fmaf(q.re, si, t2));
    }
}

extern "C" void kernel_launch(void* const* d_in, const int* in_sizes, int n_in,
                              void* d_out, int out_size, void* d_ws, size_t ws_size,
                              hipStream_t stream) {
    const float* A_real = (const float*)d_in[0];
    const float* A_imag = (const float*)d_in[1];
    const float* B_real = (const float*)d_in[2];
    const float* B_imag = (const float*)d_in[3];
    const float* P_real = (const float*)d_in[4];
    const float* P_imag = (const float*)d_in[5];
    const float* C_real = (const float*)d_in[6];
    const float* C_imag = (const float*)d_in[7];
    const float* log_dt = (const float*)d_in[8];
    float* out = (float*)d_out;

    ssm_dplr_kernel<<<256, 64, 0, stream>>>(
        A_real, A_imag, B_real, B_imag, P_real, P_imag,
        C_real, C_imag, log_dt, out);
}

// Round 3
// 133.955 us; speedup vs baseline: 4.4326x; 2.2853x over previous
//
#include <hip/hip_runtime.h>

// SSM DPLR kernel: K[h,l] = 2*Re(C_h . dA_h^l . dB_h), dA = diag(g) + q r^T.
// R2: two-level factorization l = 64*i + j:
//   K[64i+j] = 2 Re( C_i . X_j ),  X_j = dA^j dB,  C_i = C M^i,  M = dA^64.
//   M = diag(g^64) + q_n * S[n,m],  S[n,m] = sum_j g_n^{63-j} y_j[m] (Horner),
//   y_j = r^T dA^j  (row scan: y <- g.*y + (y.q) r).
// One 256-thread workgroup per head. Phases:
//   P1: wave0 scans y_j -> LDS Y;  wave1 scans X_j -> LDS Xs (col-rotated).
//   P2: all 4 waves build M rows in registers via Horner over Y.
//   P3: 31-step serial chain C_{i+1} = C_i M (partials reduced via LDS).
//   P4: K[i*64+j] = 2 Re(sum_n C_i[n] X_j[n])  (fully parallel).

#define NN 64
#define LL 2048

struct C2 { float re, im; };

__device__ __forceinline__ C2 cmul(C2 a, C2 b){ return {a.re*b.re - a.im*b.im, a.re*b.im + a.im*b.re}; }
__device__ __forceinline__ C2 csub(C2 a, C2 b){ return {a.re-b.re, a.im-b.im}; }
__device__ __forceinline__ C2 cinv(C2 a){ float s=1.0f/(a.re*a.re+a.im*a.im); return {a.re*s, -a.im*s}; }
__device__ __forceinline__ C2 cscale(float s, C2 a){ return {s*a.re, s*a.im}; }

// DPP cross-lane adds (VALU pipe). After the 6-stage sequence lane 63 holds the
// full 64-lane sum.
template<int CTRL>
__device__ __forceinline__ float dpp_add(float x){
  int t = __builtin_amdgcn_update_dpp(0, __float_as_int(x), CTRL, 0xF, 0xF, true);
  return x + __int_as_float(t);
}
__device__ __forceinline__ float wave_sum_to_lane63(float x){
  x = dpp_add<0xB1>(x);   // xor1 within quads
  x = dpp_add<0x4E>(x);   // xor2 -> quad sums
  x = dpp_add<0x124>(x);  // row_ror:4
  x = dpp_add<0x128>(x);  // row_ror:8 -> 16-lane row sums (all lanes)
  x = dpp_add<0x142>(x);  // row_bcast:15
  x = dpp_add<0x143>(x);  // row_bcast:31 -> lane 63 total
  return x;
}
__device__ __forceinline__ float bcast63(float x){
  return __int_as_float(__builtin_amdgcn_readlane(__float_as_int(x), 63));
}

__global__ __launch_bounds__(256) void ssm_dplr_kernel(
    const float* __restrict__ A_real, const float* __restrict__ A_imag,
    const float* __restrict__ B_real, const float* __restrict__ B_imag,
    const float* __restrict__ P_real, const float* __restrict__ P_imag,
    const float* __restrict__ C_real, const float* __restrict__ C_imag,
    const float* __restrict__ log_dt, float* __restrict__ out)
{
    const int h    = blockIdx.x;
    const int t    = threadIdx.x;
    const int lane = t & 63;
    const int w    = t >> 6;

    extern __shared__ char smem[];
    float2* Y    = (float2*)smem;              // [64][64]  phases 1-2
    float2* Xs   = (float2*)(smem + 32768);    // [64][64]  phases 1,4 (col-rotated)
    float2* Cs   = (float2*)smem;              // [32][64]  phases 3-4 (aliases Y)
    float2* part = (float2*)(smem + 16384);    // [4][64]   phase 3   (aliases Y)

    // ---------------- setup: per-state constants for n = lane ----------------
    const int idx = h * NN + lane;
    const float dt = expf(log_dt[h]);
    const float c  = 0.5f * dt;

    const C2 lam = { -A_real[idx], -A_imag[idx] };
    const C2 p   = {  P_real[idx],  P_imag[idx] };
    const C2 Bv  = {  B_real[idx],  B_imag[idx] };
    const C2 Cv  = {  C_real[idx],  C_imag[idx] };
    const C2 pc  = { p.re, -p.im };

    const C2 den = { 1.0f - c*lam.re, -c*lam.im };
    const C2 d   = cinv(den);
    const C2 e   = { 1.0f + c*lam.re, c*lam.im };
    const C2 g   = cmul(d, e);                 // diagonal of dA

    // wave reductions for Sherman-Morrison scalars (each wave redundantly)
    const float p2 = p.re*p.re + p.im*p.im;
    C2 sv = cscale(p2, d);
    C2 uv = cmul(cmul(d, pc), Bv);
    #pragma unroll
    for (int off = 32; off > 0; off >>= 1) {
        sv.re += __shfl_xor(sv.re, off);
        sv.im += __shfl_xor(sv.im, off);
        uv.re += __shfl_xor(uv.re, off);
        uv.im += __shfl_xor(uv.im, off);
    }
    const C2 one_cs = { 1.0f + c*sv.re, c*sv.im };
    const C2 beta   = cscale(c, cinv(one_cs));
    const C2 bs     = cmul(beta, sv);
    const C2 gamma  = { -c*(1.0f - bs.re), c*bs.im };

    const C2 q = cmul(d, p);
    const C2 r = cmul(pc, csub(gamma, cmul(beta, g)));
    // x0 = dB
    const C2 x0 = cscale(dt, csub(cmul(d, Bv), cmul(cmul(beta, uv), q)));

    // ---------------- phase 1: two concurrent 64-step scans ----------------
    if (w == 0) {
        // row scan: y_0 = r; y_{j+1} = g.*y + (y.q) r   (y_j = r^T dA^j)
        C2 y = r;
        for (int j = 0; j < 64; ++j) {
            Y[j*64 + lane] = make_float2(y.re, y.im);
            float dr = y.re*q.re - y.im*q.im;
            float di = y.re*q.im + y.im*q.re;
            dr = wave_sum_to_lane63(dr);
            di = wave_sum_to_lane63(di);
            const float sr = bcast63(dr), si = bcast63(di);
            const float nr = g.re*y.re - g.im*y.im + sr*r.re - si*r.im;
            const float ni = g.re*y.im + g.im*y.re + sr*r.im + si*r.re;
            y.re = nr; y.im = ni;
        }
    } else if (w == 1) {
        // state scan: x_0 = dB; x_{j+1} = g.*x + (r.x) q
        C2 x = x0;
        for (int j = 0; j < 64; ++j) {
            Xs[j*64 + ((lane + j) & 63)] = make_float2(x.re, x.im);  // rotated cols
            float dr = r.re*x.re - r.im*x.im;
            float di = r.re*x.im + r.im*x.re;
            dr = wave_sum_to_lane63(dr);
            di = wave_sum_to_lane63(di);
            const float sr = bcast63(dr), si = bcast63(di);
            const float nr = g.re*x.re - g.im*x.im + sr*q.re - si*q.im;
            const float ni = g.re*x.im + g.im*x.re + sr*q.im + si*q.re;
            x.re = nr; x.im = ni;
        }
    }
    __syncthreads();

    // ---------------- phase 2: M rows [16w, 16w+16) in registers ----------------
    // M[n][m] = g_n^64 * (n==m) + q_n * S[n][m],  S = Horner_j(g_n; Y[j][m])
    C2 gk[16], qk[16];
    #pragma unroll
    for (int k = 0; k < 16; ++k) {
        const int n  = 16*w + k;
        const int i2 = h * NN + n;
        const C2 lk = { -A_real[i2], -A_imag[i2] };
        const C2 pk = {  P_real[i2],  P_imag[i2] };
        const C2 dk = cinv(C2{ 1.0f - c*lk.re, -c*lk.im });
        gk[k] = cmul(dk, C2{ 1.0f + c*lk.re, c*lk.im });
        qk[k] = cmul(dk, pk);
    }
    C2 Mk[16];
    {
        const float2 y0 = Y[lane];          // j = 0 value, same for all k
        #pragma unroll
        for (int k = 0; k < 16; ++k) Mk[k] = { y0.x, y0.y };
        for (int j = 1; j < 64; ++j) {
            const float2 yv = Y[j*64 + lane];
            #pragma unroll
            for (int k = 0; k < 16; ++k) {
                const float ar = Mk[k].re*gk[k].re - Mk[k].im*gk[k].im + yv.x;
                const float ai = Mk[k].re*gk[k].im + Mk[k].im*gk[k].re + yv.y;
                Mk[k].re = ar; Mk[k].im = ai;
            }
        }
        #pragma unroll
        for (int k = 0; k < 16; ++k) Mk[k] = cmul(qk[k], Mk[k]);
        // diagonal term: n == m(=lane)  ->  k = lane & 15 when lane>>4 == w
        if ((lane >> 4) == w) {
            const int k0 = lane & 15;
            C2 gp = gk[k0];                 // g^64 via 6 squarings
            #pragma unroll
            for (int s = 0; s < 6; ++s) gp = cmul(gp, gp);
            Mk[k0].re += gp.re; Mk[k0].im += gp.im;
        }
    }
    __syncthreads();   // Y dead; its space becomes Cs/part

    // ---------------- phase 3: C_i chain, C_{i+1} = C_i M ----------------
    if (t < 64) Cs[t] = make_float2(Cv.re, Cv.im);   // C_0 = C (thread t has n=t)
    __syncthreads();
    for (int i = 0; i < 31; ++i) {
        C2 s = {0.0f, 0.0f};
        #pragma unroll
        for (int k = 0; k < 16; ++k) {
            const float2 cn = Cs[i*64 + 16*w + k];   // uniform -> broadcast
            s.re += cn.x*Mk[k].re - cn.y*Mk[k].im;
            s.im += cn.x*Mk[k].im + cn.y*Mk[k].re;
        }
        part[w*64 + lane] = make_float2(s.re, s.im);
        __syncthreads();
        if (t < 64) {
            const float2 p0 = part[t], p1 = part[64+t], p2b = part[128+t], p3 = part[192+t];
            Cs[(i+1)*64 + t] = make_float2(p0.x+p1.x+p2b.x+p3.x, p0.y+p1.y+p2b.y+p3.y);
        }
        __syncthreads();
    }

    // ---------------- phase 4: K[64i+j] = 2 Re(sum_n C_i[n] X_j[n]) ----------------
    const int j = lane;
    float accK[8] = {0,0,0,0,0,0,0,0};
    for (int n0 = 0; n0 < 64; ++n0) {
        const float2 xv = Xs[j*64 + ((j + n0) & 63)];   // holds x_j[n0] (rotation)
        #pragma unroll
        for (int rr = 0; rr < 8; ++rr) {
            const float2 cv = Cs[(w*8 + rr)*64 + n0];   // uniform -> broadcast
            accK[rr] += cv.x*xv.x - cv.y*xv.y;
        }
    }
    float* outh = out + h * LL;
    #pragma unroll
    for (int rr = 0; rr < 8; ++rr) {
        outh[(w*8 + rr)*64 + j] = 2.0f * accK[rr];
    }
}

extern "C" void kernel_launch(void* const* d_in, const int* in_sizes, int n_in,
                              void* d_out, int out_size, void* d_ws, size_t ws_size,
                              hipStream_t stream) {
    const float* A_real = (const float*)d_in[0];
    const float* A_imag = (const float*)d_in[1];
    const float* B_real = (const float*)d_in[2];
    const float* B_imag = (const float*)d_in[3];
    const float* P_real = (const float*)d_in[4];
    const float* P_imag = (const float*)d_in[5];
    const float* C_real = (const float*)d_in[6];
    const float* C_imag = (const float*)d_in[7];
    const float* log_dt = (const float*)d_in[8];
    float* out = (float*)d_out;

    ssm_dplr_kernel<<<256, 256, 65536, stream>>>(
        A_real, A_imag, B_real, B_imag, P_real, P_imag,
        C_real, C_imag, log_dt, out);
}

// Round 5
// 123.249 us; speedup vs baseline: 4.8176x; 1.0869x over previous
//
#include <hip/hip_runtime.h>

// SSM DPLR kernel: K[h,l] = 2*Re(C_h . dA_h^l . dB_h), dA = diag(g) + q r^T.
// R4 (= R3 fixed): l = 64*i + j factorization:
//   K[64i+j] = 2 Re( C_i . X_j ),  X_j = dA^j dB,  C_i = C M^i,  M = dA^64.
//  - scans replaced by triangular-Toeplitz scalar solves (readlane + DPP wave_shr)
//  - M = dA^64 in closed divided-difference form:
//      M[n][m] = d_{nm} g64_n + q_n r_m [ (g64_n - g64_m) + (T(g_n)-T(g_m)) ] / (g_n - g_m)
//      M[n][n] = g64_n + q_n r_n ( 64 g_n^63 + T'(g_n) ),  T(z) = sum_i tau_i z^{63-i}
//  - 512 threads/block (8 waves), M rows in registers, 1 barrier per chain step.

#define LL 2048

struct C2 { float re, im; };

__device__ __forceinline__ C2 cmul(C2 a, C2 b){ return {a.re*b.re - a.im*b.im, a.re*b.im + a.im*b.re}; }
__device__ __forceinline__ C2 cadd(C2 a, C2 b){ return {a.re+b.re, a.im+b.im}; }
__device__ __forceinline__ C2 csub(C2 a, C2 b){ return {a.re-b.re, a.im-b.im}; }
__device__ __forceinline__ C2 cinv(C2 a){ float s=1.0f/(a.re*a.re+a.im*a.im); return {a.re*s, -a.im*s}; }
__device__ __forceinline__ C2 cscale(float s, C2 a){ return {s*a.re, s*a.im}; }
__device__ __forceinline__ C2 ld2(float2 v){ return {v.x, v.y}; }
__device__ __forceinline__ float2 st2(C2 v){ return make_float2(v.re, v.im); }

template<int CTRL>
__device__ __forceinline__ float dpp_add(float x){
  int t = __builtin_amdgcn_update_dpp(0, __float_as_int(x), CTRL, 0xF, 0xF, true);
  return x + __int_as_float(t);
}
// lane 63 ends with the full 64-lane sum
__device__ __forceinline__ float wave_sum63(float x){
  x = dpp_add<0xB1>(x);   // quad_perm xor1
  x = dpp_add<0x4E>(x);   // quad_perm xor2
  x = dpp_add<0x124>(x);  // row_ror:4
  x = dpp_add<0x128>(x);  // row_ror:8
  x = dpp_add<0x142>(x);  // row_bcast:15
  x = dpp_add<0x143>(x);  // row_bcast:31
  return x;
}
__device__ __forceinline__ float bcast63(float x){
  return __int_as_float(__builtin_amdgcn_readlane(__float_as_int(x), 63));
}
__device__ __forceinline__ float rdlane(float v, int l){
  return __int_as_float(__builtin_amdgcn_readlane(__float_as_int(v), l));
}
// D[m] = S[m-1], lane0 <- 0   (wave_shr:1 = 0x138)
__device__ __forceinline__ float shr1(float x){
  return __int_as_float(__builtin_amdgcn_update_dpp(0, __float_as_int(x), 0x138, 0xF, 0xF, true));
}

__global__ __launch_bounds__(512) void ssm_dplr_kernel(
    const float* __restrict__ A_real, const float* __restrict__ A_imag,
    const float* __restrict__ B_real, const float* __restrict__ B_imag,
    const float* __restrict__ P_real, const float* __restrict__ P_imag,
    const float* __restrict__ C_real, const float* __restrict__ C_imag,
    const float* __restrict__ log_dt, float* __restrict__ out)
{
    const int h    = blockIdx.x;
    const int t    = threadIdx.x;
    const int lane = t & 63;
    const int wid  = t >> 6;     // wave 0..7

    extern __shared__ char sm[];
    float2* Abuf = (float2*)sm;              // 64x64: G (powers), later X   [32 KB]
    float2* Cs   = (float2*)(sm + 32768);    // 32x64 C_i rows               [16 KB]
    float2* prt  = (float2*)(sm + 49152);    // 2 x (8x64) partials          [ 8 KB]
    float2* gA   = (float2*)(sm + 57344);    // smalls, 64 float2 each:
    float2* qA   = gA + 64;
    float2* g64A = gA + 128;
    float2* TgA  = gA + 192;
    float2* TpA  = gA + 256;
    float2* rqA  = gA + 320;
    float2* rxA  = gA + 384;
    float2* wvA  = gA + 448;
    float2* avA  = gA + 512;
    float2* sgA  = gA + 576;
    float2* tvA  = gA + 640;

    // ---------------- setup (every wave redundantly, per-lane n = lane) ----------------
    const int idx = h * 64 + lane;
    const float dt = expf(log_dt[h]);
    const float c  = 0.5f * dt;

    const C2 lam = { -A_real[idx], -A_imag[idx] };
    const C2 p   = {  P_real[idx],  P_imag[idx] };
    const C2 Bv  = {  B_real[idx],  B_imag[idx] };
    const C2 Cv  = {  C_real[idx],  C_imag[idx] };
    const C2 pc  = { p.re, -p.im };

    const C2 d = cinv(C2{ 1.0f - c*lam.re, -c*lam.im });
    const C2 g = cmul(d, C2{ 1.0f + c*lam.re, c*lam.im });   // diag of dA

    // Sherman-Morrison scalars via DPP wave sums
    C2 sv = cscale(p.re*p.re + p.im*p.im, d);
    C2 uv = cmul(cmul(d, pc), Bv);
    sv.re = bcast63(wave_sum63(sv.re)); sv.im = bcast63(wave_sum63(sv.im));
    uv.re = bcast63(wave_sum63(uv.re)); uv.im = bcast63(wave_sum63(uv.im));

    const C2 beta  = cscale(c, cinv(C2{ 1.0f + c*sv.re, c*sv.im }));
    const C2 bs    = cmul(beta, sv);
    const C2 gamma = { -c*(1.0f - bs.re), c*bs.im };

    const C2 q  = cmul(d, p);
    const C2 r  = cmul(pc, csub(gamma, cmul(beta, g)));
    const C2 x0 = cscale(dt, csub(cmul(d, Bv), cmul(cmul(beta, uv), q)));  // dB

    // power chain
    const C2 g2  = cmul(g,  g);
    const C2 g4  = cmul(g2, g2);
    const C2 g8  = cmul(g4, g4);
    const C2 g16 = cmul(g8, g8);
    const C2 g32 = cmul(g16,g16);
    const C2 g64 = cmul(g32,g32);

    if (wid == 0) {
        gA[lane]   = st2(g);
        qA[lane]   = st2(q);
        g64A[lane] = st2(g64);
        rqA[lane]  = st2(cmul(r, q));
        rxA[lane]  = st2(cmul(r, x0));
    }
    __syncthreads();

    // ---------------- G-gen: G[j][n] = g_n^j, rows j in [8w, 8w+8) ----------------
    {
        C2 cur = {1.0f, 0.0f};
        if (wid & 1) cur = g8;
        if (wid & 2) cur = cmul(cur, g16);
        if (wid & 4) cur = cmul(cur, g32);          // g^(8*wid)
        #pragma unroll
        for (int jj = 0; jj < 8; ++jj) {
            const int j = 8*wid + jj;
            Abuf[j*64 + ((lane + j) & 63)] = st2(cur);   // rotated columns
            cur = cmul(cur, g);
        }
    }
    __syncthreads();

    // ---------------- w_j, a_j via transpose-sum (lane = j) ----------------
    {
        C2 accw = {0,0}, acca = {0,0};
        #pragma unroll
        for (int kk = 0; kk < 8; ++kk) {
            const int n = 8*wid + kk;
            const C2 Gv = ld2(Abuf[lane*64 + ((n + lane) & 63)]);
            const C2 fq = ld2(rqA[n]);      // uniform
            const C2 fx = ld2(rxA[n]);      // uniform
            accw = cadd(accw, cmul(Gv, fq));
            acca = cadd(acca, cmul(Gv, fx));
        }
        prt[wid*64 + lane]       = st2(accw);
        prt[512 + wid*64 + lane] = st2(acca);
    }
    __syncthreads();
    if (t < 64) {
        C2 sw = {0,0}, sa = {0,0};
        #pragma unroll
        for (int w2 = 0; w2 < 8; ++w2) {
            sw = cadd(sw, ld2(prt[w2*64 + t]));
            sa = cadd(sa, ld2(prt[512 + w2*64 + t]));
        }
        wvA[t] = st2(sw);
        avA[t] = st2(sa);
    }
    __syncthreads();

    // ---------------- triangular-Toeplitz solves: sigma (wave0), tau (wave1) ----------------
    // v_j = rhs_j + sum_{i<j} w_{j-1-i} v_i
    if (wid < 2) {
        const float2 rhs = (wid == 0) ? avA[lane] : wvA[lane];
        C2 va = ld2(rhs);
        const C2 wl = ld2(wvA[lane]);
        C2 wsh = { shr1(wl.re), shr1(wl.im) };     // w_{m-1}, lane0 = 0
        float so_re = 0.0f, so_im = 0.0f;
        for (int j = 0; j < 64; ++j) {
            const float sr = rdlane(va.re, j);
            const float si = rdlane(va.im, j);
            if (lane == j) { so_re = sr; so_im = si; }
            va.re += wsh.re*sr - wsh.im*si;
            va.im += wsh.re*si + wsh.im*sr;
            wsh.re = shr1(wsh.re);
            wsh.im = shr1(wsh.im);
        }
        if (wid == 0) sgA[lane] = make_float2(so_re, so_im);
        else          tvA[lane] = make_float2(so_re, so_im);
    }
    __syncthreads();

    // ---------------- wave0: T(g_n), T'(g_n); wave1: X rebuild ----------------
    if (wid == 0) {
        // T(z) = sum_{i=0}^{62} tau_i z^{63-i} = z * P(z); P, P' by Horner
        C2 pp = ld2(tvA[0]);
        C2 dd = {0,0};
        for (int i = 1; i <= 62; ++i) {
            const C2 ti = ld2(tvA[i]);
            dd = cadd(cmul(dd, g), pp);
            pp = cadd(cmul(pp, g), ti);
        }
        TgA[lane] = st2(cmul(g, pp));              // T(g)
        TpA[lane] = st2(cadd(pp, cmul(g, dd)));    // T'(g) = P + z P'
    } else if (wid == 1) {
        // X_0 = dB; X_{j+1} = g.*X_j + sigma_j * q
        C2 x = x0;
        for (int j = 0; j < 64; ++j) {
            Abuf[j*64 + ((lane + j) & 63)] = st2(x);
            const C2 sj = ld2(sgA[j]);             // uniform
            const float nr = g.re*x.re - g.im*x.im + sj.re*q.re - sj.im*q.im;
            const float ni = g.re*x.im + g.im*x.re + sj.re*q.im + sj.im*q.re;
            x.re = nr; x.im = ni;
        }
    }
    __syncthreads();

    // ---------------- M build: Mk[k] = M[8*wid+k][m],  m = lane ----------------
    // M[n][m] = d_{nm} g64_n + q_n r_m [ (g64_n - g64_m) + (T(g_n) - T(g_m)) ] / (g_n - g_m)
    // M[n][n] = g64_n + q_n r_n ( 64 g_n^63 + T'(g_n) )
    C2 Mk[8];
    {
        const C2 Tgm = ld2(TgA[lane]);
        #pragma unroll
        for (int k = 0; k < 8; ++k) {
            const int n = 8*wid + k;
            const C2 gn   = ld2(gA[n]);            // uniform reads
            const C2 qn   = ld2(qA[n]);
            const C2 g64n = ld2(g64A[n]);
            const C2 Tgn  = ld2(TgA[n]);
            const C2 idm  = cinv(csub(gn, g));     // n==lane -> inf/NaN, overwritten below
            const C2 num  = cmul(r, cadd(csub(g64n, g64), csub(Tgn, Tgm)));
            Mk[k] = cmul(cmul(qn, num), idm);
        }
        if ((lane >> 3) == wid) {                  // diagonal element owned by this thread
            const int k0 = lane & 7;
            const C2 Tp  = ld2(TpA[lane]);
            const C2 g63 = cmul(g64, cinv(g));
            const C2 S   = cmul(r, cadd(cscale(64.0f, g63), Tp));
            Mk[k0] = cadd(g64, cmul(q, S));
        }
    }

    // ---------------- C chain: C_{i+1} = C_i M  (C_i per-lane in regs, all waves) ----------------
    C2 Ci = Cv;                                    // C_0
    for (int i = 0; i < 32; ++i) {
        if (wid == 0) Cs[i*64 + lane] = st2(Ci);
        if (i == 31) break;
        C2 acc = {0,0};
        #pragma unroll
        for (int k = 0; k < 8; ++k) {
            const float cr = rdlane(Ci.re, 8*wid + k);
            const float cim= rdlane(Ci.im, 8*wid + k);
            acc.re += cr*Mk[k].re - cim*Mk[k].im;
            acc.im += cr*Mk[k].im + cim*Mk[k].re;
        }
        prt[(i & 1)*512 + wid*64 + lane] = st2(acc);
        __syncthreads();
        C2 nc = {0,0};
        #pragma unroll
        for (int w2 = 0; w2 < 8; ++w2) {
            const float2 pv = prt[(i & 1)*512 + w2*64 + lane];
            nc.re += pv.x; nc.im += pv.y;
        }
        Ci = nc;
    }
    __syncthreads();

    // ---------------- output: K[64i+j] = 2 Re( sum_n C_i[n] X_j[n] ), i in [4w,4w+4) ----------------
    {
        const int j = lane;
        float accK[4] = {0,0,0,0};
        #pragma unroll 8
        for (int n = 0; n < 64; ++n) {
            const float2 xv = Abuf[j*64 + ((n + j) & 63)];
            #pragma unroll
            for (int rr = 0; rr < 4; ++rr) {
                const float2 cv = Cs[(4*wid + rr)*64 + n];   // uniform
                accK[rr] += cv.x*xv.x - cv.y*xv.y;
            }
        }
        float* outh = out + h * LL;
        #pragma unroll
        for (int rr = 0; rr < 4; ++rr) {
            outh[(4*wid + rr)*64 + j] = 2.0f * accK[rr];
        }
    }
}

extern "C" void kernel_launch(void* const* d_in, const int* in_sizes, int n_in,
                              void* d_out, int out_size, void* d_ws, size_t ws_size,
                              hipStream_t stream) {
    const float* A_real = (const float*)d_in[0];
    const float* A_imag = (const float*)d_in[1];
    const float* B_real = (const float*)d_in[2];
    const float* B_imag = (const float*)d_in[3];
    const float* P_real = (const float*)d_in[4];
    const float* P_imag = (const float*)d_in[5];
    const float* C_real = (const float*)d_in[6];
    const float* C_imag = (const float*)d_in[7];
    const float* log_dt = (const float*)d_in[8];
    float* out = (float*)d_out;

    const size_t lds = 57344 + 704*sizeof(float2);   // 62976 B
    ssm_dplr_kernel<<<256, 512, lds, stream>>>(
        A_real, A_imag, B_real, B_imag, P_real, P_imag,
        C_real, C_imag, log_dt, out);
}